// Round 7
// baseline (380.781 us; speedup 1.0000x reference)
//
#include <hip/hip_runtime.h>
#include <hip/hip_bf16.h>
#include <stdint.h>

#define T      3072
#define CH     64
#define HEADS  32
#define BM     128
#define BN     64
#define NIT    (T / BN)

typedef unsigned short u16;
typedef short short8 __attribute__((ext_vector_type(8)));   // 8 bf16 as i16
typedef float floatx4 __attribute__((ext_vector_type(4)));

__device__ __forceinline__ unsigned pk2(float a, float b) {  // 2 fp32 -> packed bf16x2 (RNE)
  union { __hip_bfloat162 h; unsigned u; } cv;
  cv.h = __float22bfloat162_rn(float2{a, b});
  return cv.u;
}

__device__ __forceinline__ void gl_lds16(const void* g, void* l) {
  __builtin_amdgcn_global_load_lds(
      (const __attribute__((address_space(1))) uint32_t*)g,
      (__attribute__((address_space(3))) uint32_t*)l, 16, 0, 0);
}

// Cross-quad exchanges (VALU, gfx950): swap rows crosswise between two VGPRs.
__device__ __forceinline__ void pl32swap(unsigned& x, unsigned& y) {
#if __has_builtin(__builtin_amdgcn_permlane32_swap)
  auto r = __builtin_amdgcn_permlane32_swap(x, y, false, false);
  x = r[0]; y = r[1];
#else
  asm("v_permlane32_swap_b32 %0, %1" : "+v"(x), "+v"(y));
#endif
}
__device__ __forceinline__ void pl16swap(unsigned& x, unsigned& y) {
#if __has_builtin(__builtin_amdgcn_permlane16_swap)
  auto r = __builtin_amdgcn_permlane16_swap(x, y, false, false);
  x = r[0]; y = r[1];
#else
  asm("v_permlane16_swap_b32 %0, %1" : "+v"(x), "+v"(y));
#endif
}

// ---------- prepass: Q/K transpose (ch,t)->(t,ch) + V flat cast, all bf16 ----------
// grid (48 t-tiles, 32 heads, 3 roles), 256 threads   [round-3 verified version]
__global__ __launch_bounds__(256) void qktrans(
    const float* __restrict__ qkv, u16* __restrict__ Qt, u16* __restrict__ Kt,
    u16* __restrict__ Vo) {
  __shared__ __align__(16) u16 tl[64][72];            // [t][c], pad to 144B stride
  const int ttile = blockIdx.x, hh = blockIdx.y, role = blockIdx.z;
  const int b = hh >> 3, h = hh & 7;
  const int t0 = ttile * 64;
  const int tid = threadIdx.x;

  if (role == 2) {                                     // V: no transpose, flat cast
    const float* vsrc = qkv + (size_t)(b * 1536 + 1024 + h * CH) * T;
    u16* vdst = Vo + (size_t)(b * 512 + h * CH) * T;
#pragma unroll
    for (int p = 0; p < 2; ++p) {
      const int r = p * 32 + (tid >> 3);
      const int off = (tid & 7) * 8;
      const float4* s4 = (const float4*)(vsrc + (size_t)r * T + t0 + off);
      float4 a = s4[0], c = s4[1];
      uint4 o;
      o.x = pk2(a.x, a.y); o.y = pk2(a.z, a.w);
      o.z = pk2(c.x, c.y); o.w = pk2(c.z, c.w);
      *(uint4*)(vdst + (size_t)r * T + t0 + off) = o;
    }
    return;
  }

  const float* src = qkv + (size_t)(b * 1536 + role * 512 + h * CH) * T;
  const float scale = (role == 0) ? 0.18033688011112042f : 1.0f;  // (1/8)*log2e on Q

#pragma unroll
  for (int p = 0; p < 2; ++p) {                        // 32 c-rows per pass
    const int c0 = p * 32 + ((tid >> 4) << 1);         // even
    const int ts = (tid & 15) * 4;                     // 256B contiguous per c-row
    float4 a = *(const float4*)(src + (size_t)c0 * T + t0 + ts);
    float4 c = *(const float4*)(src + (size_t)(c0 + 1) * T + t0 + ts);
    *(unsigned*)&tl[ts + 0][c0] = pk2(a.x * scale, c.x * scale);
    *(unsigned*)&tl[ts + 1][c0] = pk2(a.y * scale, c.y * scale);
    *(unsigned*)&tl[ts + 2][c0] = pk2(a.z * scale, c.z * scale);
    *(unsigned*)&tl[ts + 3][c0] = pk2(a.w * scale, c.w * scale);
  }
  __syncthreads();
  u16* dst = (role == 0 ? Qt : Kt) + (size_t)hh * T * CH;
#pragma unroll
  for (int q = 0; q < 2; ++q) {                        // 1KB/wave contiguous stores
    const int t = q * 32 + (tid >> 3);
    const int cc = (tid & 7) * 8;
    uint4 v = *(const uint4*)&tl[t][cc];
    *(uint4*)(dst + (size_t)(t0 + t) * CH + cc) = v;
  }
}

// ---------- flash attention v10: K via LDS (16 KB dbuf), V-frags direct from ----------
// ---------- global (L1-cached, 16B/lane contiguous); head-grouped XCD swizzle ----------
// grid 768 (1-D, lin%8 == head%8 so each XCD's L2 holds 4 heads of K+V = 3 MB),
// 512 threads = 8 waves; 16 KB LDS; 1 barrier/iter.
__global__ __launch_bounds__(512, 6) void attn(
    const u16* __restrict__ Qt, const u16* __restrict__ Kt,
    const u16* __restrict__ Vg, float* __restrict__ out) {
  __shared__ __align__(16) u16 KB[2][BN * CH];    // [s][c] 8 KB each, xor-swizzled

  // head-grouped decode: all 24 q-tiles of head hh share lin%8 (same XCD slot)
  const int lin = blockIdx.x;
  const int jj = lin >> 3, xcd = lin & 7;
  const int qtile = jj % 24;
  const int hh = xcd + 8 * (jj / 24);

  const int tid = threadIdx.x;
  const int wave = tid >> 6, lane = tid & 63;     // wave 0..7
  const int l15 = lane & 15, quad = lane >> 4;
  const int t0 = qtile * BM + wave * 16;          // 16 q-rows per wave
  const int b = hh >> 3, h = hh & 7;

  const u16* Qh = Qt + (size_t)hh * T * CH;
  const u16* Kh = Kt + (size_t)hh * T * CH;
  const u16* Vh = Vg + (size_t)hh * CH * T;

  // Q B-frag resident: B[n=t=l15][k=kc*32+quad*8+j]
  short8 qf[2];
#pragma unroll
  for (int kc = 0; kc < 2; ++kc)
    qf[kc] = *(const short8*)(Qh + (size_t)(t0 + l15) * CH + kc * 32 + quad * 8);

  // all-ones bf16 B-frag for row-sum MFMA
  const short8 ones = {0x3F80, 0x3F80, 0x3F80, 0x3F80, 0x3F80, 0x3F80, 0x3F80, 0x3F80};

  floatx4 oacc[4] = {};
  floatx4 lacc = {0.f, 0.f, 0.f, 0.f};

  // K staging: 512 threads x 16B = 8 KB tile; xor swizzle phys_cb = cb ^ f(row)
  const int srow = tid >> 3;
  const int scb = (tid & 7) ^ ((srow + 2 * (srow >> 3)) & 7);
  const int swl = (l15 + 2 * (l15 >> 3)) & 7;
  const int wsl = wave * 512;                     // wave-uniform LDS slot base (u16)

#define STAGE_K(kb, s0) \
  gl_lds16(Kh + (size_t)((s0) + srow) * CH + scb * 8, &KB[kb][wsl])

  // per-lane V base: lane (quad,l15) reads V[c = mt*16+l15][s = it*64 + ks*32 + quad*8]
  const u16* Vp = Vh + (size_t)l15 * T + quad * 8;

  STAGE_K(0, 0);

  for (int it = 0; it < NIT; ++it) {
    const int cur = it & 1;
    __syncthreads();                                   // KB[cur] ready
    if (it + 1 < NIT) STAGE_K(cur ^ 1, (it + 1) * BN); // async prefetch

    const u16* KL = KB[cur];

    // S^T = K Q^T : A=K frag (LDS), B=Q frag (regs).
    // sacc[nt][r] = S[t=l15][s = nt*16 + quad*4 + r]
    floatx4 sacc[4];
#pragma unroll
    for (int nt = 0; nt < 4; ++nt) {
      const int ph0 = quad ^ swl ^ ((nt & 1) * 4);
      const int base = (nt * 16 + l15) * CH;
      const short8 kf0 = *(const short8*)(KL + base + ph0 * 8);
      const short8 kf1 = *(const short8*)(KL + base + (ph0 ^ 4) * 8);
      floatx4 z = {0.f, 0.f, 0.f, 0.f};
      z = __builtin_amdgcn_mfma_f32_16x16x32_bf16(kf0, qf[0], z, 0, 0, 0);
      z = __builtin_amdgcn_mfma_f32_16x16x32_bf16(kf1, qf[1], z, 0, 0, 0);
      sacc[nt] = z;
    }

    // static softmax: packed P words stay in registers
    unsigned Apk[4], Bpk[4];
#pragma unroll
    for (int nt = 0; nt < 4; ++nt) {
      floatx4 sv = sacc[nt];
      float p0 = __builtin_amdgcn_exp2f(sv[0]);
      float p1 = __builtin_amdgcn_exp2f(sv[1]);
      float p2 = __builtin_amdgcn_exp2f(sv[2]);
      float p3 = __builtin_amdgcn_exp2f(sv[3]);
      Apk[nt] = pk2(p0, p1);
      Bpk[nt] = pk2(p2, p3);
    }

    // O = P V^T : A=P via permlane swaps; B=V read DIRECT from global (L1-resident:
    // 8 KB tile re-read by all 8 waves this iteration). Loads are independent of
    // softmax results, so the compiler can issue them early and hide L2 latency.
    const u16* Vit = Vp + it * BN;
#pragma unroll
    for (int ks = 0; ks < 2; ++ks) {
      unsigned a0 = Apk[2 * ks], a1 = Apk[2 * ks + 1];
      unsigned b0 = Bpk[2 * ks], b1 = Bpk[2 * ks + 1];
      pl32swap(a0, a1); pl16swap(a0, a1);   // a0 -> word d0, a1 -> word d2
      pl32swap(b0, b1); pl16swap(b0, b1);   // b0 -> word d1, b1 -> word d3
      union { uint4 u; short8 s; } pw;
      pw.u.x = a0; pw.u.y = b0; pw.u.z = a1; pw.u.w = b1;
      const short8 pf = pw.s;
      lacc = __builtin_amdgcn_mfma_f32_16x16x32_bf16(pf, ones, lacc, 0, 0, 0);
#pragma unroll
      for (int mt = 0; mt < 4; ++mt) {
        const short8 vf = *(const short8*)(Vit + (size_t)(mt * 16) * T + ks * 32);
        oacc[mt] = __builtin_amdgcn_mfma_f32_16x16x32_bf16(pf, vf, oacc[mt], 0, 0, 0);
      }
    }
  }

  // epilogue: lacc[r] holds rowsum(t = t0 + quad*4 + r) in every l15 column
  float linv[4];
#pragma unroll
  for (int r = 0; r < 4; ++r) linv[r] = 1.0f / lacc[r];

  // O rows t = t0 + quad*4 + r ; cols c = mt*16 + l15 ; float4 over r
  const int tg = t0 + quad * 4;
  const int band = tg >> 10, tt = tg & 1023;
  float* obase = out + (size_t)band * (4 * 512 * 1024)
                     + (size_t)b * (512 * 1024)
                     + (size_t)(h * CH) * 1024 + tt;
#pragma unroll
  for (int mt = 0; mt < 4; ++mt) {
    const int c = mt * 16 + l15;
    float4 v;
    v.x = oacc[mt][0] * linv[0];
    v.y = oacc[mt][1] * linv[1];
    v.z = oacc[mt][2] * linv[2];
    v.w = oacc[mt][3] * linv[3];
    *(float4*)(obase + (size_t)c * 1024) = v;
  }
}

extern "C" void kernel_launch(void* const* d_in, const int* in_sizes, int n_in,
                              void* d_out, int out_size, void* d_ws, size_t ws_size,
                              hipStream_t stream) {
  (void)in_sizes; (void)n_in; (void)out_size; (void)ws_size;
  const float* qkv = (const float*)d_in[0];
  u16* Qt = (u16*)d_ws;                                 // 3 x 12.6 MB bf16
  u16* Kt = Qt + (size_t)HEADS * T * CH;
  u16* Vo = Kt + (size_t)HEADS * T * CH;
  float* out = (float*)d_out;

  qktrans<<<dim3(T / 64, HEADS, 3), 256, 0, stream>>>(qkv, Qt, Kt, Vo);
  attn<<<dim3(768), 512, 0, stream>>>(Qt, Kt, Vo, out);
}

// Round 9
// 210.585 us; speedup vs baseline: 1.8082x; 1.8082x over previous
//
#include <hip/hip_runtime.h>
#include <hip/hip_bf16.h>
#include <stdint.h>

#define T      3072
#define CH     64
#define HEADS  32
#define BM     128
#define BN     64
#define NIT    (T / BN)

typedef unsigned short u16;
typedef short short8 __attribute__((ext_vector_type(8)));   // 8 bf16 as i16
typedef float floatx4 __attribute__((ext_vector_type(4)));

__device__ __forceinline__ unsigned pk2(float a, float b) {  // 2 fp32 -> packed bf16x2 (RNE)
  union { __hip_bfloat162 h; unsigned u; } cv;
  cv.h = __float22bfloat162_rn(float2{a, b});
  return cv.u;
}

__device__ __forceinline__ void gl_lds16(const void* g, void* l) {
  __builtin_amdgcn_global_load_lds(
      (const __attribute__((address_space(1))) uint32_t*)g,
      (__attribute__((address_space(3))) uint32_t*)l, 16, 0, 0);
}

// Cross-quad exchanges (VALU, gfx950): swap rows crosswise between two VGPRs.
__device__ __forceinline__ void pl32swap(unsigned& x, unsigned& y) {
#if __has_builtin(__builtin_amdgcn_permlane32_swap)
  auto r = __builtin_amdgcn_permlane32_swap(x, y, false, false);
  x = r[0]; y = r[1];
#else
  asm("v_permlane32_swap_b32 %0, %1" : "+v"(x), "+v"(y));
#endif
}
__device__ __forceinline__ void pl16swap(unsigned& x, unsigned& y) {
#if __has_builtin(__builtin_amdgcn_permlane16_swap)
  auto r = __builtin_amdgcn_permlane16_swap(x, y, false, false);
  x = r[0]; y = r[1];
#else
  asm("v_permlane16_swap_b32 %0, %1" : "+v"(x), "+v"(y));
#endif
}

// ---------- prepass: Q/K transpose (ch,t)->(t,ch) + V flat cast, all bf16 ----------
// grid (48 t-tiles, 32 heads, 3 roles), 256 threads   [round-3 verified version]
__global__ __launch_bounds__(256) void qktrans(
    const float* __restrict__ qkv, u16* __restrict__ Qt, u16* __restrict__ Kt,
    u16* __restrict__ Vo) {
  __shared__ __align__(16) u16 tl[64][72];            // [t][c], pad to 144B stride
  const int ttile = blockIdx.x, hh = blockIdx.y, role = blockIdx.z;
  const int b = hh >> 3, h = hh & 7;
  const int t0 = ttile * 64;
  const int tid = threadIdx.x;

  if (role == 2) {                                     // V: no transpose, flat cast
    const float* vsrc = qkv + (size_t)(b * 1536 + 1024 + h * CH) * T;
    u16* vdst = Vo + (size_t)(b * 512 + h * CH) * T;
#pragma unroll
    for (int p = 0; p < 2; ++p) {
      const int r = p * 32 + (tid >> 3);
      const int off = (tid & 7) * 8;
      const float4* s4 = (const float4*)(vsrc + (size_t)r * T + t0 + off);
      float4 a = s4[0], c = s4[1];
      uint4 o;
      o.x = pk2(a.x, a.y); o.y = pk2(a.z, a.w);
      o.z = pk2(c.x, c.y); o.w = pk2(c.z, c.w);
      *(uint4*)(vdst + (size_t)r * T + t0 + off) = o;
    }
    return;
  }

  const float* src = qkv + (size_t)(b * 1536 + role * 512 + h * CH) * T;
  const float scale = (role == 0) ? 0.18033688011112042f : 1.0f;  // (1/8)*log2e on Q

#pragma unroll
  for (int p = 0; p < 2; ++p) {                        // 32 c-rows per pass
    const int c0 = p * 32 + ((tid >> 4) << 1);         // even
    const int ts = (tid & 15) * 4;                     // 256B contiguous per c-row
    float4 a = *(const float4*)(src + (size_t)c0 * T + t0 + ts);
    float4 c = *(const float4*)(src + (size_t)(c0 + 1) * T + t0 + ts);
    *(unsigned*)&tl[ts + 0][c0] = pk2(a.x * scale, c.x * scale);
    *(unsigned*)&tl[ts + 1][c0] = pk2(a.y * scale, c.y * scale);
    *(unsigned*)&tl[ts + 2][c0] = pk2(a.z * scale, c.z * scale);
    *(unsigned*)&tl[ts + 3][c0] = pk2(a.w * scale, c.w * scale);
  }
  __syncthreads();
  u16* dst = (role == 0 ? Qt : Kt) + (size_t)hh * T * CH;
#pragma unroll
  for (int q = 0; q < 2; ++q) {                        // 1KB/wave contiguous stores
    const int t = q * 32 + (tid >> 3);
    const int cc = (tid & 7) * 8;
    uint4 v = *(const uint4*)&tl[t][cc];
    *(uint4*)(dst + (size_t)(t0 + t) * CH + cc) = v;
  }
}

// ---------- flash attention v11: tq=2 (32 rows/wave), 4-wave blocks ----------
// Each K/V fragment read from LDS feeds BOTH tq sub-tiles -> LDS bytes per row
// halved vs v6.  3 blocks/CU = 3 independent barrier groups; launch_bounds(256,3)
// gives a 170-VGPR cap so the ~140-reg state does NOT spill (v4's failure mode).
// grid (24 q-tiles, 32 heads), 256 threads = 4 waves; 32 KB LDS.
__global__ __launch_bounds__(256, 3) void attn(
    const u16* __restrict__ Qt, const u16* __restrict__ Kt,
    const u16* __restrict__ Vg, float* __restrict__ out) {
  __shared__ __align__(16) u16 KB[2][BN * CH];    // [s][c] 8 KB each, xor-swizzled
  __shared__ __align__(16) u16 VB[2][CH * BN];    // [c][s] 8 KB each, xor-swizzled

  const int qtile = blockIdx.x, hh = blockIdx.y;
  const int tid = threadIdx.x;
  const int wave = tid >> 6, lane = tid & 63;     // wave 0..3
  const int l15 = lane & 15, quad = lane >> 4;
  const int t0 = qtile * BM + wave * 32;          // 32 q-rows per wave
  const int b = hh >> 3, h = hh & 7;

  const u16* Qh = Qt + (size_t)hh * T * CH;
  const u16* Kh = Kt + (size_t)hh * T * CH;
  const u16* Vh = Vg + (size_t)hh * CH * T;

  // Q B-frags resident: B[n=t=l15(+16tq)][k=kc*32+quad*8+j]
  short8 qf[2][2];
#pragma unroll
  for (int tq = 0; tq < 2; ++tq)
#pragma unroll
    for (int kc = 0; kc < 2; ++kc)
      qf[tq][kc] = *(const short8*)(Qh + (size_t)(t0 + tq * 16 + l15) * CH + kc * 32 + quad * 8);

  // all-ones bf16 B-frag for row-sum MFMA
  const short8 ones = {0x3F80, 0x3F80, 0x3F80, 0x3F80, 0x3F80, 0x3F80, 0x3F80, 0x3F80};

  floatx4 oacc[2][4] = {};
  floatx4 lacc[2] = {};

  // staging: 512 16B-slots per tensor, 2 K + 2 V per thread (issue j covers
  // slots j*256 + wave*64 + lane); swizzle phys_cb = cb ^ ((row + 2*(row>>3))&7)
  int sr[2], sc[2];
#pragma unroll
  for (int j = 0; j < 2; ++j) {
    const int p = j * 256 + wave * 64 + lane;
    sr[j] = p >> 3;
    sc[j] = (p & 7) ^ ((sr[j] + 2 * (sr[j] >> 3)) & 7);
  }
  const int swl = (l15 + 2 * (l15 >> 3)) & 7;

#define STAGE(buf, s0)                                                              \
  do {                                                                              \
    _Pragma("unroll")                                                               \
    for (int j = 0; j < 2; ++j)                                                     \
      gl_lds16(Kh + (size_t)((s0) + sr[j]) * CH + sc[j] * 8,                        \
               &KB[buf][(j * 256 + wave * 64) * 8]);                                \
    _Pragma("unroll")                                                               \
    for (int j = 0; j < 2; ++j)                                                     \
      gl_lds16(Vh + (size_t)sr[j] * T + (s0) + sc[j] * 8,                           \
               &VB[buf][(j * 256 + wave * 64) * 8]);                                \
  } while (0)

  STAGE(0, 0);

  for (int it = 0; it < NIT; ++it) {
    const int cur = it & 1;
    __syncthreads();                                   // buf[cur] ready
    if (it + 1 < NIT) STAGE(cur ^ 1, (it + 1) * BN);   // async prefetch

    const u16* KL = KB[cur];
    const u16* VL = VB[cur];

    // S^T = K Q^T : A=K frag (LDS, shared by both tq), B=Q frag (regs).
    // sacc[tq][nt][r] = S[t = l15+16tq][s = nt*16 + quad*4 + r]
    floatx4 sacc[2][4];
    __builtin_amdgcn_s_setprio(1);
#pragma unroll
    for (int nt = 0; nt < 4; ++nt) {
      const int ph0 = quad ^ swl ^ ((nt & 1) * 4);
      const int base = (nt * 16 + l15) * CH;
      const short8 kf0 = *(const short8*)(KL + base + ph0 * 8);
      const short8 kf1 = *(const short8*)(KL + base + (ph0 ^ 4) * 8);
#pragma unroll
      for (int tq = 0; tq < 2; ++tq) {
        floatx4 z = {0.f, 0.f, 0.f, 0.f};
        z = __builtin_amdgcn_mfma_f32_16x16x32_bf16(kf0, qf[tq][0], z, 0, 0, 0);
        z = __builtin_amdgcn_mfma_f32_16x16x32_bf16(kf1, qf[tq][1], z, 0, 0, 0);
        sacc[tq][nt] = z;
      }
    }
    __builtin_amdgcn_s_setprio(0);

    // static softmax: packed P words stay in registers
    unsigned Apk[2][4], Bpk[2][4];
#pragma unroll
    for (int tq = 0; tq < 2; ++tq)
#pragma unroll
      for (int nt = 0; nt < 4; ++nt) {
        floatx4 sv = sacc[tq][nt];
        float p0 = __builtin_amdgcn_exp2f(sv[0]);
        float p1 = __builtin_amdgcn_exp2f(sv[1]);
        float p2 = __builtin_amdgcn_exp2f(sv[2]);
        float p3 = __builtin_amdgcn_exp2f(sv[3]);
        Apk[tq][nt] = pk2(p0, p1);
        Bpk[tq][nt] = pk2(p2, p3);
      }

    // O = P V^T : A=P via permlane swaps; each V frag read serves both tq.
    __builtin_amdgcn_s_setprio(1);
#pragma unroll
    for (int ks = 0; ks < 2; ++ks) {
      short8 pf[2];
#pragma unroll
      for (int tq = 0; tq < 2; ++tq) {
        unsigned a0 = Apk[tq][2 * ks], a1 = Apk[tq][2 * ks + 1];
        unsigned b0 = Bpk[tq][2 * ks], b1 = Bpk[tq][2 * ks + 1];
        pl32swap(a0, a1); pl16swap(a0, a1);   // a0 -> word d0, a1 -> word d2
        pl32swap(b0, b1); pl16swap(b0, b1);   // b0 -> word d1, b1 -> word d3
        union { uint4 u; short8 s; } pw;
        pw.u.x = a0; pw.u.y = b0; pw.u.z = a1; pw.u.w = b1;
        pf[tq] = pw.s;
        lacc[tq] = __builtin_amdgcn_mfma_f32_16x16x32_bf16(pf[tq], ones, lacc[tq], 0, 0, 0);
      }
#pragma unroll
      for (int mt = 0; mt < 4; ++mt) {
        const int ph = quad ^ swl ^ ((mt & 1) * 4) ^ (ks * 4);
        const short8 vf = *(const short8*)(VL + (mt * 16 + l15) * BN + ph * 8);
        oacc[0][mt] = __builtin_amdgcn_mfma_f32_16x16x32_bf16(pf[0], vf, oacc[0][mt], 0, 0, 0);
        oacc[1][mt] = __builtin_amdgcn_mfma_f32_16x16x32_bf16(pf[1], vf, oacc[1][mt], 0, 0, 0);
      }
    }
    __builtin_amdgcn_s_setprio(0);
  }

  // epilogue: lacc[tq][r] holds rowsum(t = t0 + tq*16 + quad*4 + r) per l15 col
  float linv[2][4];
#pragma unroll
  for (int tq = 0; tq < 2; ++tq)
#pragma unroll
    for (int r = 0; r < 4; ++r) linv[tq][r] = 1.0f / lacc[tq][r];

  // O rows t = t0 + tq*16 + quad*4 + r ; cols c = mt*16 + l15 ; float4 over r
#pragma unroll
  for (int tq = 0; tq < 2; ++tq) {
    const int tgr = t0 + tq * 16 + quad * 4;
    const int band = tgr >> 10, tt = tgr & 1023;
    float* obase = out + (size_t)band * (4 * 512 * 1024)
                       + (size_t)b * (512 * 1024)
                       + (size_t)(h * CH) * 1024 + tt;
#pragma unroll
    for (int mt = 0; mt < 4; ++mt) {
      const int c = mt * 16 + l15;
      float4 v;
      v.x = oacc[tq][mt][0] * linv[tq][0];
      v.y = oacc[tq][mt][1] * linv[tq][1];
      v.z = oacc[tq][mt][2] * linv[tq][2];
      v.w = oacc[tq][mt][3] * linv[tq][3];
      *(float4*)(obase + (size_t)c * 1024) = v;
    }
  }
}

extern "C" void kernel_launch(void* const* d_in, const int* in_sizes, int n_in,
                              void* d_out, int out_size, void* d_ws, size_t ws_size,
                              hipStream_t stream) {
  (void)in_sizes; (void)n_in; (void)out_size; (void)ws_size;
  const float* qkv = (const float*)d_in[0];
  u16* Qt = (u16*)d_ws;                                 // 3 x 12.6 MB bf16
  u16* Kt = Qt + (size_t)HEADS * T * CH;
  u16* Vo = Kt + (size_t)HEADS * T * CH;
  float* out = (float*)d_out;

  qktrans<<<dim3(T / 64, HEADS, 3), 256, 0, stream>>>(qkv, Qt, Kt, Vo);
  attn<<<dim3(T / BM, HEADS), 256, 0, stream>>>(Qt, Kt, Vo, out);
}

// Round 10
// 209.794 us; speedup vs baseline: 1.8150x; 1.0038x over previous
//
#include <hip/hip_runtime.h>
#include <hip/hip_bf16.h>
#include <stdint.h>

#define T      3072
#define CH     64
#define HEADS  32
#define BM     128
#define BN     64
#define NIT    (T / BN)

typedef unsigned short u16;
typedef short short8 __attribute__((ext_vector_type(8)));   // 8 bf16 as i16
typedef float floatx4 __attribute__((ext_vector_type(4)));

__device__ __forceinline__ unsigned pk2(float a, float b) {  // 2 fp32 -> packed bf16x2 (RNE)
  union { __hip_bfloat162 h; unsigned u; } cv;
  cv.h = __float22bfloat162_rn(float2{a, b});
  return cv.u;
}

__device__ __forceinline__ void gl_lds16(const void* g, void* l) {
  __builtin_amdgcn_global_load_lds(
      (const __attribute__((address_space(1))) uint32_t*)g,
      (__attribute__((address_space(3))) uint32_t*)l, 16, 0, 0);
}

// Cross-quad exchanges (VALU, gfx950): swap rows crosswise between two VGPRs.
__device__ __forceinline__ void pl32swap(unsigned& x, unsigned& y) {
#if __has_builtin(__builtin_amdgcn_permlane32_swap)
  auto r = __builtin_amdgcn_permlane32_swap(x, y, false, false);
  x = r[0]; y = r[1];
#else
  asm("v_permlane32_swap_b32 %0, %1" : "+v"(x), "+v"(y));
#endif
}
__device__ __forceinline__ void pl16swap(unsigned& x, unsigned& y) {
#if __has_builtin(__builtin_amdgcn_permlane16_swap)
  auto r = __builtin_amdgcn_permlane16_swap(x, y, false, false);
  x = r[0]; y = r[1];
#else
  asm("v_permlane16_swap_b32 %0, %1" : "+v"(x), "+v"(y));
#endif
}

// ---------- prepass: Q/K transpose (ch,t)->(t,ch) + V flat cast, all bf16 ----------
// grid (48 t-tiles, 32 heads, 3 roles), 256 threads   [round-3 verified version]
__global__ __launch_bounds__(256) void qktrans(
    const float* __restrict__ qkv, u16* __restrict__ Qt, u16* __restrict__ Kt,
    u16* __restrict__ Vo) {
  __shared__ __align__(16) u16 tl[64][72];            // [t][c], pad to 144B stride
  const int ttile = blockIdx.x, hh = blockIdx.y, role = blockIdx.z;
  const int b = hh >> 3, h = hh & 7;
  const int t0 = ttile * 64;
  const int tid = threadIdx.x;

  if (role == 2) {                                     // V: no transpose, flat cast
    const float* vsrc = qkv + (size_t)(b * 1536 + 1024 + h * CH) * T;
    u16* vdst = Vo + (size_t)(b * 512 + h * CH) * T;
#pragma unroll
    for (int p = 0; p < 2; ++p) {
      const int r = p * 32 + (tid >> 3);
      const int off = (tid & 7) * 8;
      const float4* s4 = (const float4*)(vsrc + (size_t)r * T + t0 + off);
      float4 a = s4[0], c = s4[1];
      uint4 o;
      o.x = pk2(a.x, a.y); o.y = pk2(a.z, a.w);
      o.z = pk2(c.x, c.y); o.w = pk2(c.z, c.w);
      *(uint4*)(vdst + (size_t)r * T + t0 + off) = o;
    }
    return;
  }

  const float* src = qkv + (size_t)(b * 1536 + role * 512 + h * CH) * T;
  const float scale = (role == 0) ? 0.18033688011112042f : 1.0f;  // (1/8)*log2e on Q

#pragma unroll
  for (int p = 0; p < 2; ++p) {                        // 32 c-rows per pass
    const int c0 = p * 32 + ((tid >> 4) << 1);         // even
    const int ts = (tid & 15) * 4;                     // 256B contiguous per c-row
    float4 a = *(const float4*)(src + (size_t)c0 * T + t0 + ts);
    float4 c = *(const float4*)(src + (size_t)(c0 + 1) * T + t0 + ts);
    *(unsigned*)&tl[ts + 0][c0] = pk2(a.x * scale, c.x * scale);
    *(unsigned*)&tl[ts + 1][c0] = pk2(a.y * scale, c.y * scale);
    *(unsigned*)&tl[ts + 2][c0] = pk2(a.z * scale, c.z * scale);
    *(unsigned*)&tl[ts + 3][c0] = pk2(a.w * scale, c.w * scale);
  }
  __syncthreads();
  u16* dst = (role == 0 ? Qt : Kt) + (size_t)hh * T * CH;
#pragma unroll
  for (int q = 0; q < 2; ++q) {                        // 1KB/wave contiguous stores
    const int t = q * 32 + (tid >> 3);
    const int cc = (tid & 7) * 8;
    uint4 v = *(const uint4*)&tl[t][cc];
    *(uint4*)(dst + (size_t)(t0 + t) * CH + cc) = v;
  }
}

// ---------- flash attention v12: v11 + T3/T4 counted-vmcnt deep pipeline ----------
// Triple-buffered K/V, prefetch 2 tiles deep; per-iter sync is
// s_waitcnt vmcnt(4) + raw s_barrier (tile i+1's 4 loads stay in flight across
// the barrier).  Only the last iter drains vmcnt(0).  48 KB LDS -> 3 blocks/CU.
// grid (24 q-tiles, 32 heads), 256 threads = 4 waves, tq=2 (32 rows/wave).
__global__ __launch_bounds__(256, 3) void attn(
    const u16* __restrict__ Qt, const u16* __restrict__ Kt,
    const u16* __restrict__ Vg, float* __restrict__ out) {
  __shared__ __align__(16) u16 KB[3][BN * CH];    // [s][c] 8 KB each, xor-swizzled
  __shared__ __align__(16) u16 VB[3][CH * BN];    // [c][s] 8 KB each, xor-swizzled

  const int qtile = blockIdx.x, hh = blockIdx.y;
  const int tid = threadIdx.x;
  const int wave = tid >> 6, lane = tid & 63;     // wave 0..3
  const int l15 = lane & 15, quad = lane >> 4;
  const int t0 = qtile * BM + wave * 32;          // 32 q-rows per wave
  const int b = hh >> 3, h = hh & 7;

  const u16* Qh = Qt + (size_t)hh * T * CH;
  const u16* Kh = Kt + (size_t)hh * T * CH;
  const u16* Vh = Vg + (size_t)hh * CH * T;

  // Q B-frags resident: B[n=t=l15(+16tq)][k=kc*32+quad*8+j]
  short8 qf[2][2];
#pragma unroll
  for (int tq = 0; tq < 2; ++tq)
#pragma unroll
    for (int kc = 0; kc < 2; ++kc)
      qf[tq][kc] = *(const short8*)(Qh + (size_t)(t0 + tq * 16 + l15) * CH + kc * 32 + quad * 8);

  // all-ones bf16 B-frag for row-sum MFMA
  const short8 ones = {0x3F80, 0x3F80, 0x3F80, 0x3F80, 0x3F80, 0x3F80, 0x3F80, 0x3F80};

  floatx4 oacc[2][4] = {};
  floatx4 lacc[2] = {};

  // staging: 512 16B-slots per tensor, 2 K + 2 V per thread (issue j covers
  // slots j*256 + wave*64 + lane); swizzle phys_cb = cb ^ ((row + 2*(row>>3))&7)
  int sr[2], sc[2];
#pragma unroll
  for (int j = 0; j < 2; ++j) {
    const int p = j * 256 + wave * 64 + lane;
    sr[j] = p >> 3;
    sc[j] = (p & 7) ^ ((sr[j] + 2 * (sr[j] >> 3)) & 7);
  }
  const int swl = (l15 + 2 * (l15 >> 3)) & 7;

  // 4 gl_lds per thread per STAGE -> vmcnt unit is 4; 2 STAGEs in flight = 8.
#define STAGE(buf, s0)                                                              \
  do {                                                                              \
    _Pragma("unroll")                                                               \
    for (int j = 0; j < 2; ++j)                                                     \
      gl_lds16(Kh + (size_t)((s0) + sr[j]) * CH + sc[j] * 8,                        \
               &KB[buf][(j * 256 + wave * 64) * 8]);                                \
    _Pragma("unroll")                                                               \
    for (int j = 0; j < 2; ++j)                                                     \
      gl_lds16(Vh + (size_t)sr[j] * T + (s0) + sc[j] * 8,                           \
               &VB[buf][(j * 256 + wave * 64) * 8]);                                \
  } while (0)

  STAGE(0, 0);
  STAGE(1, BN);

  int cur = 0, nxt = 2;                                // compute buf, stage buf
  for (int it = 0; it < NIT; ++it) {
    // tile it's 4 loads are the oldest outstanding; leave tile it+1's in flight.
    if (it + 1 < NIT) {
      asm volatile("s_waitcnt vmcnt(4)" ::: "memory");
    } else {
      asm volatile("s_waitcnt vmcnt(0)" ::: "memory");
    }
    __builtin_amdgcn_s_barrier();                      // all waves: buf[cur] ready
    __builtin_amdgcn_sched_barrier(0);                 // pin ds_reads behind waitcnt
    if (it + 2 < NIT) STAGE(nxt, (it + 2) * BN);       // overwrites buf[(it-1)%3]: drained

    const u16* KL = KB[cur];
    const u16* VL = VB[cur];

    // S^T = K Q^T : A=K frag (LDS, shared by both tq), B=Q frag (regs).
    // sacc[tq][nt][r] = S[t = l15+16tq][s = nt*16 + quad*4 + r]
    floatx4 sacc[2][4];
    __builtin_amdgcn_s_setprio(1);
#pragma unroll
    for (int nt = 0; nt < 4; ++nt) {
      const int ph0 = quad ^ swl ^ ((nt & 1) * 4);
      const int base = (nt * 16 + l15) * CH;
      const short8 kf0 = *(const short8*)(KL + base + ph0 * 8);
      const short8 kf1 = *(const short8*)(KL + base + (ph0 ^ 4) * 8);
#pragma unroll
      for (int tq = 0; tq < 2; ++tq) {
        floatx4 z = {0.f, 0.f, 0.f, 0.f};
        z = __builtin_amdgcn_mfma_f32_16x16x32_bf16(kf0, qf[tq][0], z, 0, 0, 0);
        z = __builtin_amdgcn_mfma_f32_16x16x32_bf16(kf1, qf[tq][1], z, 0, 0, 0);
        sacc[tq][nt] = z;
      }
    }
    __builtin_amdgcn_s_setprio(0);

    // static softmax: packed P words stay in registers
    unsigned Apk[2][4], Bpk[2][4];
#pragma unroll
    for (int tq = 0; tq < 2; ++tq)
#pragma unroll
      for (int nt = 0; nt < 4; ++nt) {
        floatx4 sv = sacc[tq][nt];
        float p0 = __builtin_amdgcn_exp2f(sv[0]);
        float p1 = __builtin_amdgcn_exp2f(sv[1]);
        float p2 = __builtin_amdgcn_exp2f(sv[2]);
        float p3 = __builtin_amdgcn_exp2f(sv[3]);
        Apk[tq][nt] = pk2(p0, p1);
        Bpk[tq][nt] = pk2(p2, p3);
      }

    // O = P V^T : A=P via permlane swaps; each V frag read serves both tq.
    __builtin_amdgcn_s_setprio(1);
#pragma unroll
    for (int ks = 0; ks < 2; ++ks) {
      short8 pf[2];
#pragma unroll
      for (int tq = 0; tq < 2; ++tq) {
        unsigned a0 = Apk[tq][2 * ks], a1 = Apk[tq][2 * ks + 1];
        unsigned b0 = Bpk[tq][2 * ks], b1 = Bpk[tq][2 * ks + 1];
        pl32swap(a0, a1); pl16swap(a0, a1);   // a0 -> word d0, a1 -> word d2
        pl32swap(b0, b1); pl16swap(b0, b1);   // b0 -> word d1, b1 -> word d3
        union { uint4 u; short8 s; } pw;
        pw.u.x = a0; pw.u.y = b0; pw.u.z = a1; pw.u.w = b1;
        pf[tq] = pw.s;
        lacc[tq] = __builtin_amdgcn_mfma_f32_16x16x32_bf16(pf[tq], ones, lacc[tq], 0, 0, 0);
      }
#pragma unroll
      for (int mt = 0; mt < 4; ++mt) {
        const int ph = quad ^ swl ^ ((mt & 1) * 4) ^ (ks * 4);
        const short8 vf = *(const short8*)(VL + (mt * 16 + l15) * BN + ph * 8);
        oacc[0][mt] = __builtin_amdgcn_mfma_f32_16x16x32_bf16(pf[0], vf, oacc[0][mt], 0, 0, 0);
        oacc[1][mt] = __builtin_amdgcn_mfma_f32_16x16x32_bf16(pf[1], vf, oacc[1][mt], 0, 0, 0);
      }
    }
    __builtin_amdgcn_s_setprio(0);

    cur = (cur == 2) ? 0 : cur + 1;
    nxt = (nxt == 2) ? 0 : nxt + 1;
  }

  // epilogue: lacc[tq][r] holds rowsum(t = t0 + tq*16 + quad*4 + r) per l15 col
  float linv[2][4];
#pragma unroll
  for (int tq = 0; tq < 2; ++tq)
#pragma unroll
    for (int r = 0; r < 4; ++r) linv[tq][r] = 1.0f / lacc[tq][r];

  // O rows t = t0 + tq*16 + quad*4 + r ; cols c = mt*16 + l15 ; float4 over r
#pragma unroll
  for (int tq = 0; tq < 2; ++tq) {
    const int tgr = t0 + tq * 16 + quad * 4;
    const int band = tgr >> 10, tt = tgr & 1023;
    float* obase = out + (size_t)band * (4 * 512 * 1024)
                       + (size_t)b * (512 * 1024)
                       + (size_t)(h * CH) * 1024 + tt;
#pragma unroll
    for (int mt = 0; mt < 4; ++mt) {
      const int c = mt * 16 + l15;
      float4 v;
      v.x = oacc[tq][mt][0] * linv[tq][0];
      v.y = oacc[tq][mt][1] * linv[tq][1];
      v.z = oacc[tq][mt][2] * linv[tq][2];
      v.w = oacc[tq][mt][3] * linv[tq][3];
      *(float4*)(obase + (size_t)c * 1024) = v;
    }
  }
}

extern "C" void kernel_launch(void* const* d_in, const int* in_sizes, int n_in,
                              void* d_out, int out_size, void* d_ws, size_t ws_size,
                              hipStream_t stream) {
  (void)in_sizes; (void)n_in; (void)out_size; (void)ws_size;
  const float* qkv = (const float*)d_in[0];
  u16* Qt = (u16*)d_ws;                                 // 3 x 12.6 MB bf16
  u16* Kt = Qt + (size_t)HEADS * T * CH;
  u16* Vo = Kt + (size_t)HEADS * T * CH;
  float* out = (float*)d_out;

  qktrans<<<dim3(T / 64, HEADS, 3), 256, 0, stream>>>(qkv, Qt, Kt, Vo);
  attn<<<dim3(T / BM, HEADS), 256, 0, stream>>>(Qt, Kt, Vo, out);
}